// Round 1
// baseline (155.052 us; speedup 1.0000x reference)
//
#include <hip/hip_runtime.h>

// Problem: B=32, N=384, C=768, H=12, hd=64, scale=1/8, EPS=1e-6
#define BB 32
#define NN 384
#define CC 768
#define HH 12
#define HD 64

typedef __attribute__((ext_vector_type(4))) float f32x4;
typedef __attribute__((ext_vector_type(8))) __bf16 bf16x8;
typedef __attribute__((ext_vector_type(4))) __bf16 bf16x4;

static __device__ __forceinline__ f32x4 mfma16(bf16x8 a, bf16x8 b, f32x4 c) {
    return __builtin_amdgcn_mfma_f32_16x16x32_bf16(a, b, c, 0, 0, 0);
}

// ---------------- f32 -> bf16 convert (with optional scale) ----------------
__global__ void cvt_kernel(const float* __restrict__ src, __bf16* __restrict__ dst,
                           int n8, float scale) {
    int i = blockIdx.x * blockDim.x + threadIdx.x;
    if (i >= n8) return;
    f32x4 a = *(const f32x4*)(src + (size_t)i * 8);
    f32x4 b = *(const f32x4*)(src + (size_t)i * 8 + 4);
    bf16x8 o;
#pragma unroll
    for (int j = 0; j < 4; ++j) { o[j] = (__bf16)(a[j] * scale); o[j + 4] = (__bf16)(b[j] * scale); }
    *(bf16x8*)(dst + (size_t)i * 8) = o;
}

// ---------------- GEMM: C[M][ncol] = A[M][768] * Bw[ncol][768]^T + bias ----
// EPI==0: qkv gemm -> Q/K natural bf16 [tok][1536], V transposed bf16 [B,H,64,384]
// EPI==1: proj gemm -> f32 out [tok][768]
template <int EPI>
__global__ __launch_bounds__(256, 2) void gemm_kernel(
    const __bf16* __restrict__ A, const __bf16* __restrict__ Bw,
    const float* __restrict__ bias,
    __bf16* __restrict__ qkbuf, __bf16* __restrict__ vtbuf,
    float* __restrict__ fout) {
    __shared__ __bf16 Alds[128][72];  // +8 pad -> 2-way max bank conflict on b128 reads
    __shared__ __bf16 Blds[128][72];

    const int tid = threadIdx.x;
    const int l = tid & 63;
    const int w = tid >> 6;
    const int g = l >> 4, q16 = l & 15;
    const int mb = blockIdx.x * 128;
    const int nb = blockIdx.y * 128;
    const int wrb = (w >> 1) * 64;
    const int wcb = (w & 1) * 64;
    const int srow = tid >> 3;       // 0..31
    const int sc8 = (tid & 7) * 8;   // 0..56

    const __bf16* Ab = A + (size_t)mb * CC;
    const __bf16* Bb = Bw + (size_t)nb * CC;

    f32x4 acc[4][4] = {};
    bf16x8 sa[4], sb[4];

    // prologue: stage tile 0 into regs
#pragma unroll
    for (int p = 0; p < 4; ++p) {
        sa[p] = *(const bf16x8*)&Ab[(size_t)(p * 32 + srow) * CC + sc8];
        sb[p] = *(const bf16x8*)&Bb[(size_t)(p * 32 + srow) * CC + sc8];
    }

    for (int kt = 0; kt < 12; ++kt) {
        // write staged regs -> LDS
#pragma unroll
        for (int p = 0; p < 4; ++p) {
            *(bf16x8*)&Alds[p * 32 + srow][sc8] = sa[p];
            *(bf16x8*)&Blds[p * 32 + srow][sc8] = sb[p];
        }
        __syncthreads();
        // issue next-tile global loads; latency hides under MFMA below
        if (kt < 11) {
            const int kn = (kt + 1) * 64 + sc8;
#pragma unroll
            for (int p = 0; p < 4; ++p) {
                sa[p] = *(const bf16x8*)&Ab[(size_t)(p * 32 + srow) * CC + kn];
                sb[p] = *(const bf16x8*)&Bb[(size_t)(p * 32 + srow) * CC + kn];
            }
        }
#pragma unroll
        for (int c = 0; c < 2; ++c) {
            bf16x8 af[4], bf_[4];
#pragma unroll
            for (int m = 0; m < 4; ++m)
                af[m] = *(const bf16x8*)&Alds[wrb + m * 16 + q16][c * 32 + g * 8];
#pragma unroll
            for (int n = 0; n < 4; ++n)
                bf_[n] = *(const bf16x8*)&Blds[wcb + n * 16 + q16][c * 32 + g * 8];
#pragma unroll
            for (int m = 0; m < 4; ++m)
#pragma unroll
                for (int n = 0; n < 4; ++n)
                    acc[m][n] = mfma16(af[m], bf_[n], acc[m][n]);
        }
        __syncthreads();
    }

    // epilogue. C/D layout: col = l&15 (+16*n), row = 4*g + r (+16*m)  [m89-verified]
    if constexpr (EPI == 0) {
        const int bbatch = mb / NN;   // block never straddles a batch (128 | 384)
        const int tokb = mb % NN;
#pragma unroll
        for (int n = 0; n < 4; ++n) {
            const int colb = nb + wcb + n * 16;
            const int col = colb + q16;
            float bs = bias[col];
            if (colb < 2 * CC) {
                if (colb < CC) bs *= 0.125f;  // Q pre-scaled by softmax scale
#pragma unroll
                for (int m = 0; m < 4; ++m) {
                    const int row = mb + wrb + m * 16 + g * 4;
#pragma unroll
                    for (int r = 0; r < 4; ++r)
                        qkbuf[(size_t)(row + r) * 1536 + col] = (__bf16)(acc[m][n][r] + bs);
                }
            } else {
                const int dd = (col - 2 * CC) & 63;
                const int hh = (colb - 2 * CC) >> 6;
                __bf16* vp = vtbuf + ((size_t)(bbatch * HH + hh) * HD + dd) * NN;
#pragma unroll
                for (int m = 0; m < 4; ++m) {
                    const int tok = tokb + wrb + m * 16 + g * 4;
                    bf16x4 pk;
#pragma unroll
                    for (int r = 0; r < 4; ++r) pk[r] = (__bf16)(acc[m][n][r] + bs);
                    *(bf16x4*)&vp[tok] = pk;
                }
            }
        }
    } else {
#pragma unroll
        for (int n = 0; n < 4; ++n) {
            const int col = nb + wcb + n * 16 + q16;
            const float bs = bias[col];
#pragma unroll
            for (int m = 0; m < 4; ++m)
#pragma unroll
                for (int r = 0; r < 4; ++r)
                    fout[(size_t)(mb + wrb + m * 16 + g * 4 + r) * CC + col] = acc[m][n][r] + bs;
        }
    }
}

// ---------------- fused policy-softmax attention ----------------
// grid (3 qblocks, H, B); 8 waves x 16 queries. Swapped QK^T: S^T = K*Q^T so
// each lane owns one query column -> softmax nearly all in-lane; S^T C/D regs
// feed PV B-operand lane-locally (shared k-slot bijection for A and B).
__global__ __launch_bounds__(512, 2) void attn_kernel(
    const __bf16* __restrict__ qkbuf, const __bf16* __restrict__ vtbuf,
    const float* __restrict__ policy, __bf16* __restrict__ attb) {
    __shared__ __bf16 Klds[NN][72];      // 55296 B
    __shared__ __bf16 Vlds[HD][NN + 8];  // 50176 B
    __shared__ float pol[NN];            // 1536 B

    const int tid = threadIdx.x;
    const int l = tid & 63;
    const int w = tid >> 6;
    const int g = l >> 4, q16 = l & 15;
    const int qblk = blockIdx.x;
    const int h = blockIdx.y;
    const int b = blockIdx.z;

    if (tid < NN) pol[tid] = policy[b * NN + tid];

    const __bf16* kg = qkbuf + (size_t)b * NN * 1536 + CC + h * HD;
#pragma unroll
    for (int p = 0; p < 6; ++p) {
        const int s = p * 512 + tid;
        const int row = s >> 3, c8 = (s & 7) * 8;
        *(bf16x8*)&Klds[row][c8] = *(const bf16x8*)&kg[(size_t)row * 1536 + c8];
    }
    const __bf16* vg = vtbuf + (size_t)(b * HH + h) * HD * NN;
#pragma unroll
    for (int p = 0; p < 6; ++p) {
        const int s = p * 512 + tid;
        const int d = s / 48, tk = (s % 48) * 8;
        *(bf16x8*)&Vlds[d][tk] = *(const bf16x8*)&vg[(size_t)s * 8];
    }
    __syncthreads();

    const int qrow = qblk * 128 + w * 16 + q16;  // this lane's query (column)
    const __bf16* qg = qkbuf + ((size_t)b * NN + qrow) * 1536 + h * HD;
    bf16x8 qf0 = *(const bf16x8*)&qg[g * 8];
    bf16x8 qf1 = *(const bf16x8*)&qg[32 + g * 8];

    // S^T: 24 key-tiles; lane holds keys 16t+4g+r for its query q16
    f32x4 st[24];
#pragma unroll
    for (int t = 0; t < 24; ++t) {
        bf16x8 k0 = *(const bf16x8*)&Klds[t * 16 + q16][g * 8];
        bf16x8 k1 = *(const bf16x8*)&Klds[t * 16 + q16][32 + g * 8];
        f32x4 z = {0.f, 0.f, 0.f, 0.f};
        st[t] = mfma16(k1, qf1, mfma16(k0, qf0, z));
    }

    // max over ALL keys (reference takes max before masking)
    float mx = -1e30f;
#pragma unroll
    for (int t = 0; t < 24; ++t)
#pragma unroll
        for (int r = 0; r < 4; ++r) mx = fmaxf(mx, st[t][r]);
    mx = fmaxf(mx, __shfl_xor(mx, 16));
    mx = fmaxf(mx, __shfl_xor(mx, 32));

    // e = keep ? exp(s-m) : 0 ;  keep = policy[key] | (key==q)   (policy is binary)
    float sum = 0.f;
#pragma unroll
    for (int t = 0; t < 24; ++t) {
#pragma unroll
        for (int r = 0; r < 4; ++r) {
            const int key = t * 16 + g * 4 + r;
            const bool keep = (pol[key] > 0.5f) || (key == qrow);
            const float e = keep ? __expf(st[t][r] - mx) : 0.f;
            st[t][r] = e;
            sum += e;
        }
    }
    sum += __shfl_xor(sum, 16);
    sum += __shfl_xor(sum, 32);
    const float dinv = 1.f / (sum + 1e-6f);  // (EPS/n numerator term ~1e-7: dropped)

    // PV: out^T[d][q] = sum_k V^T[d][k] * P^T[k][q]; P slots are lane-local
    f32x4 oacc[4] = {};
#pragma unroll
    for (int c = 0; c < 12; ++c) {
        bf16x8 pf;
#pragma unroll
        for (int r = 0; r < 4; ++r) {
            pf[r] = (__bf16)st[2 * c][r];
            pf[r + 4] = (__bf16)st[2 * c + 1][r];
        }
#pragma unroll
        for (int db = 0; db < 4; ++db) {
            bf16x4 v0 = *(const bf16x4*)&Vlds[db * 16 + q16][c * 32 + g * 4];
            bf16x4 v1 = *(const bf16x4*)&Vlds[db * 16 + q16][c * 32 + 16 + g * 4];
            bf16x8 vf;
#pragma unroll
            for (int r = 0; r < 4; ++r) { vf[r] = v0[r]; vf[r + 4] = v1[r]; }
            oacc[db] = mfma16(vf, pf, oacc[db]);
        }
    }

    __bf16* op = attb + ((size_t)b * NN + qrow) * CC + h * HD;
#pragma unroll
    for (int db = 0; db < 4; ++db) {
        bf16x4 pk;
#pragma unroll
        for (int r = 0; r < 4; ++r) pk[r] = (__bf16)(oacc[db][r] * dinv);
        *(bf16x4*)&op[db * 16 + g * 4] = pk;
    }
}

extern "C" void kernel_launch(void* const* d_in, const int* in_sizes, int n_in,
                              void* d_out, int out_size, void* d_ws, size_t ws_size,
                              hipStream_t stream) {
    (void)in_sizes; (void)n_in; (void)out_size; (void)ws_size;
    const float* x      = (const float*)d_in[0];
    const float* policy = (const float*)d_in[1];
    const float* qkv_w  = (const float*)d_in[2];
    const float* qkv_b  = (const float*)d_in[3];
    const float* proj_w = (const float*)d_in[4];
    const float* proj_b = (const float*)d_in[5];
    float* out = (float*)d_out;

    // workspace layout (bf16), total ~94.5 MB
    __bf16* xb    = (__bf16*)d_ws;                     // 12288*768
    __bf16* wqkv  = xb + (size_t)12288 * 768;          // 2304*768
    __bf16* wproj = wqkv + (size_t)2304 * 768;         // 768*768
    __bf16* qkbuf = wproj + (size_t)768 * 768;         // 12288*1536 (Q|K)
    __bf16* vtbuf = qkbuf + (size_t)12288 * 1536;      // 32*12*64*384 (V^T)
    __bf16* attb  = vtbuf + (size_t)BB * HH * HD * NN; // 12288*768

    auto cvt = [&](const float* s, __bf16* d, size_t n, float sc) {
        const int n8 = (int)(n / 8);
        cvt_kernel<<<(n8 + 255) / 256, 256, 0, stream>>>(s, d, n8, sc);
    };
    cvt(x, xb, (size_t)12288 * 768, 1.f);
    cvt(qkv_w, wqkv, (size_t)768 * 768, 0.125f);  // Q weight rows pre-scaled
    cvt(qkv_w + (size_t)768 * 768, wqkv + (size_t)768 * 768, (size_t)1536 * 768, 1.f);
    cvt(proj_w, wproj, (size_t)768 * 768, 1.f);

    gemm_kernel<0><<<dim3(96, 18), 256, 0, stream>>>(xb, wqkv, qkv_b, qkbuf, vtbuf, nullptr);
    attn_kernel<<<dim3(3, HH, BB), 512, 0, stream>>>(qkbuf, vtbuf, policy, attb);
    gemm_kernel<1><<<dim3(96, 6), 256, 0, stream>>>(attb, wproj, proj_b, nullptr, nullptr, out);
}